// Round 8
// baseline (4517.781 us; speedup 1.0000x reference)
//
#include <hip/hip_runtime.h>
#include <hip/hip_fp16.h>

typedef _Float16 f16;
typedef unsigned int u32;
typedef unsigned long long u64;
typedef _Float16 f16x4 __attribute__((ext_vector_type(4)));
typedef _Float16 f16x8 __attribute__((ext_vector_type(8)));
typedef float f32x4 __attribute__((ext_vector_type(4)));
typedef float f32x16 __attribute__((ext_vector_type(16)));

#define SEQ   512
#define HID   512
#define NSK   1024
#define INDIM 2048
#define NWG   64
#define HSTEP 32768   // f16 per timestep, tiled layout [ug=u>>3][b][u&7]

// ---- workspace layout (bytes) ----
#define H1_OFF    0ull
#define H2_OFF    33554432ull
#define WHH0_OFF  67108864ull
#define WIH1_OFF  69206016ull
#define WHH1_OFF  71303168ull
#define FCW_OFF   73400320ull
#define BF_OFF    74448896ull   // bfold [2][64][32] f32 (16KB)
#define W0P_OFF   74465280ull   // 8 MB: [2048 col][64 wg][32 j] f16, j = gate*8+unit
#define FLG_OFF   82853888ull   // 64 per-WG flags, 64B apart (u32 stride 16)
#define SIDX_OFF  82857984ull   // [512 t][64 b] int combined gather index (128KB)

__device__ __forceinline__ float sigmoidf_(float x) {
    return 1.0f / (1.0f + __expf(-x));
}
__device__ __forceinline__ float tanhf_(float x) {
    return 2.0f * sigmoidf_(2.0f * x) - 1.0f;
}

// ---- prep: f16 weights, folded per-WG bias, transposed gather index, flags ----
__global__ __launch_bounds__(256) void prep_kernel(
    const int* __restrict__ skills, const int* __restrict__ corrects,
    const float* __restrict__ Whh0, const float* __restrict__ Wih1,
    const float* __restrict__ Whh1, const float* __restrict__ fcW,
    const float* __restrict__ bih0, const float* __restrict__ bhh0,
    const float* __restrict__ bih1, const float* __restrict__ bhh1,
    f16* __restrict__ whh0h, f16* __restrict__ wih1h,
    f16* __restrict__ whh1h, f16* __restrict__ fcwh,
    float* __restrict__ bfold, int* __restrict__ sidx, u32* __restrict__ flags)
{
    int i = blockIdx.x * 256 + threadIdx.x;
    if (i < 2048 * 512) {
        whh0h[i] = (f16)Whh0[i];
        wih1h[i] = (f16)Wih1[i];
        whh1h[i] = (f16)Whh1[i];
    }
    if (i < 1024 * 512) fcwh[i] = (f16)fcW[i];
    if (i < 4096) {
        int lyr = i >> 11, wgi = (i >> 5) & 63, j = i & 31;
        int row = ((j >> 3) << 9) + wgi * 8 + (j & 7);
        bfold[i] = lyr ? (bih1[row] + bhh1[row]) : (bih0[row] + bhh0[row]);
    }
    if (i < SEQ * 64) {
        int t = i >> 6, b = i & 63;
        int sk = skills[b * SEQ + t], co = corrects[b * SEQ + t];
        sidx[i] = (sk >= 0) ? (sk + NSK * ((co == 1) ? 0 : 1)) : -1;
    }
    if (i < 1024) flags[i] = 0;
}

// ---- W0P build: W0P[c][wg][j] = Wih0[r][c], r = (j>>3)*512 + wg*8 + (j&7) ----
__global__ __launch_bounds__(256) void w0p_kernel(
    const float* __restrict__ Wih0, f16* __restrict__ w0p)
{
    __shared__ float tl[64][65];
    const int tid = threadIdx.x;
    const int ct = blockIdx.x & 31, rt = blockIdx.x >> 5;
    const int r0 = rt * 64, c0 = ct * 64;
#pragma unroll 4
    for (int i = 0; i < 16; ++i) {
        int rr = i * 4 + (tid >> 6);
        int cc = tid & 63;
        tl[rr][cc] = Wih0[(size_t)(r0 + rr) * INDIM + c0 + cc];
    }
    __syncthreads();
    const int jh = r0 >> 9;            // gate (const in tile)
    const int wg0 = (r0 & 511) >> 3;   // first wg chunk
    for (int task = tid; task < 512; task += 256) {
        int c = task >> 3, wgl = task & 7;
        f16 tmp[8];
#pragma unroll
        for (int jl = 0; jl < 8; ++jl) tmp[jl] = (f16)tl[wgl * 8 + jl][c];
        *(f16x8*)&w0p[(size_t)(c0 + c) * 2048 + (wg0 + wgl) * 32 + jh * 8] =
            *(f16x8*)tmp;
    }
}

struct PArgs {
    const int* sidx; const f16* W0P;
    const f16* Whh0; const f16* Wih1; const f16* Whh1;
    const float* bfold;
    f16* h1; f16* h2;
    u32* flags;
};

// ---- persistent MFMA 2-layer LSTM: 64 WGs (1/CU), wave-autonomous ticks ----
// Operand-swapped MFMA: D = W(A) x h^T(B); D col = batch, rows = gate*8+unit.
// Waves: w0 = L0/b0-31, w1 = L1/b0-31, w2 = L1/b32-63, w3 = L0/b32-63.
// L0: Whh0 in VGPR (32 frags). L1: Wih1 in VGPR + Whh1 from FRAGMENT-ORDERED
// LDS (zero bank conflicts; R7 lesson). B-loads in groups of 8 to keep the
// live set ~210 VGPR so the RA keeps Wf resident (R6/R7 remat lesson).
// Cell fully in-register. No syncthreads in the loop. Per-wave LDS done flags
// -> w0 -> 1 global flag/WG (sc1); everyone polls 64 flags. NO fences (R2).
__global__ __launch_bounds__(256, 1) void lstm_mfma(PArgs a) {
    __shared__ f16 wlds1[32 * 64 * 8];  // 32KB: Whh1, fragment-ordered [f][lane][8]
    __shared__ u32 ldone[64];           // 4 used, stride 16

    const int wg   = blockIdx.x;
    const int tid  = threadIdx.x;
    const int lane = tid & 63;
    const int w    = tid >> 6;
    const bool isL1 = (w == 1 || w == 2);
    const int tl   = (w >= 2) ? 1 : 0;       // batch half
    const int n    = lane & 31;
    const int nh   = lane >> 5;
    const int b    = tl * 32 + n;            // batch (B col / cell lane)
    const int rown = ((n >> 3) << 9) + wg * 8 + (n & 7);   // weight row for A row n

    // stage Whh1 -> LDS in per-lane fragment order: wlds1[f][l] = frag(f, l)
    for (int i = tid; i < 2048; i += 256) {
        int f = i >> 6, l = i & 63;
        int ln = l & 31, lh = l >> 5;
        int rr = ((ln >> 3) << 9) + wg * 8 + (ln & 7);
        *(uint4*)&wlds1[(size_t)i * 8] =
            *(const uint4*)(a.Whh1 + (size_t)rr * HID + f * 16 + lh * 8);
    }
    if (tid < 4) ldone[tid * 16] = 0;

    // VGPR-resident weight frags (32 x f16x8 = 128 VGPR)
    const f16* WA = isL1 ? a.Wih1 : a.Whh0;
    f16x8 Wf[32];
#pragma unroll
    for (int f = 0; f < 32; ++f)
        Wf[f] = *(const f16x8*)(WA + (size_t)rown * HID + f * 16 + nh * 8);

    // bias: bf{g}[uu] for unit nh*4+uu, gate g
    float4 bf0, bf1, bf2, bf3;
    {
        const float* bp = a.bfold + (isL1 ? 2048 : 0) + wg * 32 + nh * 4;
        bf0 = *(const float4*)(bp + 0);
        bf1 = *(const float4*)(bp + 8);
        bf2 = *(const float4*)(bp + 16);
        bf3 = *(const float4*)(bp + 24);
    }

    float cst[4] = {0.0f, 0.0f, 0.0f, 0.0f};

    // L0 x-gather prefetch for t=0
    int sid = -1;
    uint2 xq0 = {0, 0}, xq1 = {0, 0}, xq2 = {0, 0}, xq3 = {0, 0};
    if (!isL1) {
        sid = a.sidx[b];
        if (sid >= 0) {
            const char* xp = (const char*)a.W0P + (size_t)sid * 4096 + wg * 64 + nh * 8;
            xq0 = *(const uint2*)(xp);
            xq1 = *(const uint2*)(xp + 16);
            xq2 = *(const uint2*)(xp + 32);
            xq3 = *(const uint2*)(xp + 48);
        }
    }

    __syncthreads();   // staging + flag init done (only pre-loop barrier)

    for (int tau = 0; tau <= SEQ; ++tau) {
        const bool active = isL1 ? (tau >= 1) : (tau < SEQ);
        if (active) {
            const int t = isL1 ? tau - 1 : tau;
            f32x16 acc;
#pragma unroll
            for (int j = 0; j < 16; ++j) acc[j] = 0.0f;

            if (tau >= 1) {
                // term 1: A = Wf (VGPR), B = h1[tau-1]; groups of 8 to cap regs
                const f16* hb1 = a.h1 + (size_t)(tau - 1) * HSTEP;
#pragma unroll
                for (int g = 0; g < 4; ++g) {
                    uint4 Bh[8];
#pragma unroll
                    for (int j = 0; j < 8; ++j)
                        Bh[j] = *(const uint4*)(hb1 + (((g * 8 + j) * 2 + nh) * 64 + b) * 8);
#pragma unroll
                    for (int j = 0; j < 8; ++j)
                        acc = __builtin_amdgcn_mfma_f32_32x32x16_f16(
                            Wf[g * 8 + j], __builtin_bit_cast(f16x8, Bh[j]), acc, 0, 0, 0);
                }
                if (isL1 && tau >= 2) {
                    // term 2: A = Whh1 from fragment-ordered LDS, B = h2[tau-2]
                    const f16* hb2 = a.h2 + (size_t)(tau - 2) * HSTEP;
#pragma unroll
                    for (int g = 0; g < 4; ++g) {
                        uint4 Bh[8];
                        f16x8 Af[8];
#pragma unroll
                        for (int j = 0; j < 8; ++j) {
                            Bh[j] = *(const uint4*)(hb2 + (((g * 8 + j) * 2 + nh) * 64 + b) * 8);
                            Af[j] = *(const f16x8*)&wlds1[(size_t)((g * 8 + j) * 64 + lane) * 8];
                        }
#pragma unroll
                        for (int j = 0; j < 8; ++j)
                            acc = __builtin_amdgcn_mfma_f32_32x32x16_f16(
                                Af[j], __builtin_bit_cast(f16x8, Bh[j]), acc, 0, 0, 0);
                    }
                }
            }

            // ---- cell, fully in-register: lane = batch b, units nh*4+uu ----
            const bool usec = isL1 ? (tau >= 2) : (tau >= 1);
            f16x4 x0 = __builtin_bit_cast(f16x4, xq0);
            f16x4 x1 = __builtin_bit_cast(f16x4, xq1);
            f16x4 x2 = __builtin_bit_cast(f16x4, xq2);
            f16x4 x3 = __builtin_bit_cast(f16x4, xq3);
            f16 hh[4];
#pragma unroll
            for (int uu = 0; uu < 4; ++uu) {
                float gi = acc[uu]      + bf0[uu] + (float)x0[uu];
                float gf = acc[4 + uu]  + bf1[uu] + (float)x1[uu];
                float gg = acc[8 + uu]  + bf2[uu] + (float)x2[uu];
                float go = acc[12 + uu] + bf3[uu] + (float)x3[uu];
                float c_ = usec ? cst[uu] : 0.0f;
                float cn = sigmoidf_(gf) * c_ + sigmoidf_(gi) * tanhf_(gg);
                float hv = sigmoidf_(go) * tanhf_(cn);
                cst[uu] = cn;
                hh[uu] = (f16)hv;
            }
            union { f16x4 h; u64 d; } hp;
            hp.h = (f16x4){hh[0], hh[1], hh[2], hh[3]};
            f16* hbase = isL1 ? a.h2 : a.h1;
            u64* dst = (u64*)(hbase + (size_t)t * HSTEP + ((wg * 64 + b) * 8 + nh * 4));
            __hip_atomic_store(dst, hp.d, __ATOMIC_RELAXED, __HIP_MEMORY_SCOPE_AGENT);
        }

        if (tau < SEQ) {
            // own stores drained -> wave-done (LDS) -> w0 aggregates -> WG flag
            asm volatile("s_waitcnt vmcnt(0)" ::: "memory");
            if (lane == 0)
                __hip_atomic_store(&ldone[w * 16], (u32)(tau + 1),
                                   __ATOMIC_RELAXED, __HIP_MEMORY_SCOPE_WORKGROUP);
            if (w == 0) {
                const u32 wantl = (u32)(tau + 1);
                int g2 = 0;
                while (true) {
                    u32 v = __hip_atomic_load(&ldone[(lane & 3) * 16],
                                              __ATOMIC_RELAXED, __HIP_MEMORY_SCOPE_WORKGROUP);
                    if (__ballot(v < wantl) == 0ull) break;
                    if (++g2 > (1 << 22)) break;    // visible failure, never hang
                }
                if (lane == 0)
                    __hip_atomic_store(&a.flags[wg * 16], (u32)(tau + 1),
                                       __ATOMIC_RELAXED, __HIP_MEMORY_SCOPE_AGENT);
            }

            // x-gather prefetch for tick tau+1 (hidden under the poll)
            if (!isL1 && tau + 1 < SEQ) {
                sid = a.sidx[(tau + 1) * 64 + b];
                if (sid >= 0) {
                    const char* xp = (const char*)a.W0P + (size_t)sid * 4096 + wg * 64 + nh * 8;
                    xq0 = *(const uint2*)(xp);
                    xq1 = *(const uint2*)(xp + 16);
                    xq2 = *(const uint2*)(xp + 32);
                    xq3 = *(const uint2*)(xp + 48);
                } else {
                    xq0 = xq1 = xq2 = xq3 = (uint2){0, 0};
                }
            }

            // global poll: 64 WG-flags, one per lane
            const u32 want = (u32)(tau + 1);
            int guard = 0;
            while (true) {
                u32 v = __hip_atomic_load(&a.flags[lane * 16],
                                          __ATOMIC_RELAXED, __HIP_MEMORY_SCOPE_AGENT);
                if (__ballot(v < want) == 0ull) break;
                __builtin_amdgcn_s_sleep(1);
                if (++guard > (1 << 20)) break;     // visible failure, never hang
            }
            // keep next tick's plain h-loads from hoisting above the poll
            asm volatile("" ::: "memory");
            __builtin_amdgcn_sched_barrier(0);
        }
    }
}

// ---- projection (MFMA): out[b][t][n] = sigmoid(h2[t][b][:] . fcW[n] + fcb[n])
// h2 tiled layout [t][ug][b][8]. block = 4 timesteps x 64 cols; wave = 16 batches.
__global__ __launch_bounds__(256) void proj_mfma(
    const f16* __restrict__ h2, const f16* __restrict__ fcwh,
    const float* __restrict__ fcb, float* __restrict__ out)
{
    const int tg = blockIdx.x >> 4;     // t-group (4 timesteps)
    const int nt = blockIdx.x & 15;     // 64-col group
    const int tid = threadIdx.x;
    const int l = tid & 63;
    const int w = tid >> 6;             // batch-tile
    const int col = l & 15;
    const int kb = l >> 4;

    f32x4 acc[4][4];
#pragma unroll
    for (int j = 0; j < 4; ++j)
#pragma unroll
        for (int v = 0; v < 4; ++v) acc[j][v] = (f32x4){0, 0, 0, 0};

    float fb[4];
#pragma unroll
    for (int v = 0; v < 4; ++v) fb[v] = fcb[nt * 64 + v * 16 + col];

#pragma unroll 2
    for (int f = 0; f < 16; ++f) {
        f16x8 Bf[4];
#pragma unroll
        for (int v = 0; v < 4; ++v) {
            int nn = nt * 64 + v * 16 + col;
            Bf[v] = *(const f16x8*)(fcwh + (size_t)nn * HID + f * 32 + kb * 8);
        }
#pragma unroll
        for (int j = 0; j < 4; ++j) {
            const f16* hp = h2 + (size_t)(tg * 4 + j) * HSTEP
                          + ((f * 4 + kb) * 64 + (w * 16 + col)) * 8;
            uint4 au = *(const uint4*)hp;
#pragma unroll
            for (int v = 0; v < 4; ++v)
                acc[j][v] = __builtin_amdgcn_mfma_f32_16x16x32_f16(
                    __builtin_bit_cast(f16x8, au), Bf[v], acc[j][v], 0, 0, 0);
        }
    }

    // epilogue: C layout col=lane&15, row=(lane>>4)*4+r
#pragma unroll
    for (int j = 0; j < 4; ++j) {
        int t = tg * 4 + j;
#pragma unroll
        for (int v = 0; v < 4; ++v) {
            int nn = nt * 64 + v * 16 + col;
#pragma unroll
            for (int r = 0; r < 4; ++r) {
                int b = w * 16 + kb * 4 + r;
                out[((size_t)b * SEQ + t) * NSK + nn] = sigmoidf_(acc[j][v][r] + fb[v]);
            }
        }
    }
}

extern "C" void kernel_launch(void* const* d_in, const int* in_sizes, int n_in,
                              void* d_out, int out_size, void* d_ws, size_t ws_size,
                              hipStream_t stream) {
    (void)in_sizes; (void)n_in; (void)out_size; (void)ws_size;

    const int*   skills   = (const int*)d_in[0];
    const int*   corrects = (const int*)d_in[1];
    const float* Wih0 = (const float*)d_in[2];
    const float* Whh0 = (const float*)d_in[3];
    const float* bih0 = (const float*)d_in[4];
    const float* bhh0 = (const float*)d_in[5];
    const float* Wih1 = (const float*)d_in[6];
    const float* Whh1 = (const float*)d_in[7];
    const float* bih1 = (const float*)d_in[8];
    const float* bhh1 = (const float*)d_in[9];
    const float* fcW  = (const float*)d_in[10];
    const float* fcb  = (const float*)d_in[11];

    char* ws = (char*)d_ws;
    f16*  h1    = (f16*)(ws + H1_OFF);
    f16*  h2    = (f16*)(ws + H2_OFF);
    f16*  whh0h = (f16*)(ws + WHH0_OFF);
    f16*  wih1h = (f16*)(ws + WIH1_OFF);
    f16*  whh1h = (f16*)(ws + WHH1_OFF);
    f16*  fcwh  = (f16*)(ws + FCW_OFF);
    float* bfold = (float*)(ws + BF_OFF);
    f16*  w0p   = (f16*)(ws + W0P_OFF);
    u32*  flags = (u32*)(ws + FLG_OFF);
    int*  sidx  = (int*)(ws + SIDX_OFF);

    prep_kernel<<<4096, 256, 0, stream>>>(skills, corrects, Whh0, Wih1, Whh1, fcW,
                                          bih0, bhh0, bih1, bhh1,
                                          whh0h, wih1h, whh1h, fcwh,
                                          bfold, sidx, flags);
    w0p_kernel<<<1024, 256, 0, stream>>>(Wih0, w0p);

    PArgs pa;
    pa.sidx = sidx; pa.W0P = w0p;
    pa.Whh0 = whh0h; pa.Wih1 = wih1h; pa.Whh1 = whh1h;
    pa.bfold = bfold; pa.h1 = h1; pa.h2 = h2;
    pa.flags = flags;

    lstm_mfma<<<NWG, 256, 0, stream>>>(pa);

    proj_mfma<<<2048, 256, 0, stream>>>(h2, fcwh, fcb, (float*)d_out);
}

// Round 9
// 4000.649 us; speedup vs baseline: 1.1293x; 1.1293x over previous
//
#include <hip/hip_runtime.h>
#include <hip/hip_fp16.h>

typedef _Float16 f16;
typedef unsigned int u32;
typedef unsigned long long u64;
typedef _Float16 f16x4 __attribute__((ext_vector_type(4)));
typedef _Float16 f16x8 __attribute__((ext_vector_type(8)));
typedef float f32x4 __attribute__((ext_vector_type(4)));
typedef float f32x16 __attribute__((ext_vector_type(16)));

#define SEQ   512
#define HID   512
#define NSK   1024
#define INDIM 2048
#define NWG   64
#define HSTEP 32768   // f16 per timestep, tiled layout [ug=u>>3][b][u&7]
#define WFRAG 16384   // f16 per matrix in wlds: [32 f][64 lane][8]

// ---- workspace layout (bytes) ----
#define H1_OFF    0ull
#define H2_OFF    33554432ull
#define WHH0_OFF  67108864ull
#define WIH1_OFF  69206016ull
#define WHH1_OFF  71303168ull
#define FCW_OFF   73400320ull
#define BF_OFF    74448896ull   // bfold [2][64][32] f32 (16KB)
#define W0P_OFF   74465280ull   // 8 MB: [2048 col][64 wg][32 j] f16, j = gate*8+unit
#define FLG_OFF   82853888ull   // 256 per-wave flags, 64B apart (u32 stride 16)
#define SIDX_OFF  82870272ull   // [512 t][64 b] int combined gather index (128KB)

__device__ __forceinline__ float sigmoidf_(float x) {
    return 1.0f / (1.0f + __expf(-x));
}
__device__ __forceinline__ float tanhf_(float x) {
    return 2.0f * sigmoidf_(2.0f * x) - 1.0f;
}

// ---- prep: f16 weights, folded per-WG bias, transposed gather index, flags ----
__global__ __launch_bounds__(256) void prep_kernel(
    const int* __restrict__ skills, const int* __restrict__ corrects,
    const float* __restrict__ Whh0, const float* __restrict__ Wih1,
    const float* __restrict__ Whh1, const float* __restrict__ fcW,
    const float* __restrict__ bih0, const float* __restrict__ bhh0,
    const float* __restrict__ bih1, const float* __restrict__ bhh1,
    f16* __restrict__ whh0h, f16* __restrict__ wih1h,
    f16* __restrict__ whh1h, f16* __restrict__ fcwh,
    float* __restrict__ bfold, int* __restrict__ sidx, u32* __restrict__ flags)
{
    int i = blockIdx.x * 256 + threadIdx.x;
    if (i < 2048 * 512) {
        whh0h[i] = (f16)Whh0[i];
        wih1h[i] = (f16)Wih1[i];
        whh1h[i] = (f16)Whh1[i];
    }
    if (i < 1024 * 512) fcwh[i] = (f16)fcW[i];
    if (i < 4096) {
        int lyr = i >> 11, wgi = (i >> 5) & 63, j = i & 31;
        int row = ((j >> 3) << 9) + wgi * 8 + (j & 7);
        bfold[i] = lyr ? (bih1[row] + bhh1[row]) : (bih0[row] + bhh0[row]);
    }
    if (i < SEQ * 64) {
        int t = i >> 6, b = i & 63;
        int sk = skills[b * SEQ + t], co = corrects[b * SEQ + t];
        sidx[i] = (sk >= 0) ? (sk + NSK * ((co == 1) ? 0 : 1)) : -1;
    }
    if (i < 4096) flags[i] = 0;
}

// ---- W0P build: W0P[c][wg][j] = Wih0[r][c], r = (j>>3)*512 + wg*8 + (j&7) ----
__global__ __launch_bounds__(256) void w0p_kernel(
    const float* __restrict__ Wih0, f16* __restrict__ w0p)
{
    __shared__ float tl[64][65];
    const int tid = threadIdx.x;
    const int ct = blockIdx.x & 31, rt = blockIdx.x >> 5;
    const int r0 = rt * 64, c0 = ct * 64;
#pragma unroll 4
    for (int i = 0; i < 16; ++i) {
        int rr = i * 4 + (tid >> 6);
        int cc = tid & 63;
        tl[rr][cc] = Wih0[(size_t)(r0 + rr) * INDIM + c0 + cc];
    }
    __syncthreads();
    const int jh = r0 >> 9;            // gate (const in tile)
    const int wg0 = (r0 & 511) >> 3;   // first wg chunk
    for (int task = tid; task < 512; task += 256) {
        int c = task >> 3, wgl = task & 7;
        f16 tmp[8];
#pragma unroll
        for (int jl = 0; jl < 8; ++jl) tmp[jl] = (f16)tl[wgl * 8 + jl][c];
        *(f16x8*)&w0p[(size_t)(c0 + c) * 2048 + (wg0 + wgl) * 32 + jh * 8] =
            *(f16x8*)tmp;
    }
}

struct PArgs {
    const int* sidx; const f16* W0P;
    const f16* Whh0; const f16* Wih1; const f16* Whh1;
    const float* bfold;
    f16* h1; f16* h2;
    u32* flags;
};

// ---- persistent MFMA 2-layer LSTM: 64 WGs (1/CU), wave-autonomous ticks ----
// Operand-swapped MFMA: D = W(A) x h^T(B); D col = batch, rows = gate*8+unit.
// Waves: w0 = L0/b0-31, w1 = L1/b0-31, w2 = L1/b32-63, w3 = L0/b32-63.
// ALL weights in fragment-ordered LDS (96KB) — structural fix for the R6/R7/R8
// register-allocator rematerialization (RA refuses to hold >=128 VGPR of
// loop-invariant frags; LDS reads are conflict-free and hide under MFMA).
// Cell fully in-register. No syncthreads in the loop. Per-WAVE global flags
// (sc1), everyone polls 256 flags (4/lane). NO fences (R2 lesson).
__global__ __launch_bounds__(256, 1) void lstm_mfma(PArgs a) {
    __shared__ f16 wlds[3 * WFRAG];     // 96KB: [m][f][lane][8]

    const int wg   = blockIdx.x;
    const int tid  = threadIdx.x;
    const int lane = tid & 63;
    const int w    = tid >> 6;
    const bool isL1 = (w == 1 || w == 2);
    const int tl   = (w >= 2) ? 1 : 0;       // batch half
    const int n    = lane & 31;
    const int nh   = lane >> 5;
    const int b    = tl * 32 + n;            // batch (B col / cell lane)

    // stage Whh0 / Wih1 / Whh1 -> LDS, per-lane fragment order:
    // wlds[m][f][l] = M[row(l&31)][f*16 + (l>>5)*8 .. +8], row(ln) per A-row map
    for (int i = tid; i < 3 * 2048; i += 256) {
        int m = i >> 11, rem = i & 2047;
        int f = rem >> 6, l = rem & 63;
        int ln = l & 31, lh = l >> 5;
        int rr = ((ln >> 3) << 9) + wg * 8 + (ln & 7);
        const f16* src = (m == 0) ? a.Whh0 : ((m == 1) ? a.Wih1 : a.Whh1);
        *(uint4*)&wlds[(size_t)i * 8] =
            *(const uint4*)(src + (size_t)rr * HID + f * 16 + lh * 8);
    }

    const f16* wb1 = wlds + (size_t)(isL1 ? 1 : 0) * WFRAG;   // term-1 matrix
    const f16* wb2 = wlds + (size_t)2 * WFRAG;                // Whh1 (term 2)

    // bias: bf{g}[uu] for unit nh*4+uu, gate g
    float4 bf0, bf1, bf2, bf3;
    {
        const float* bp = a.bfold + (isL1 ? 2048 : 0) + wg * 32 + nh * 4;
        bf0 = *(const float4*)(bp + 0);
        bf1 = *(const float4*)(bp + 8);
        bf2 = *(const float4*)(bp + 16);
        bf3 = *(const float4*)(bp + 24);
    }

    float cst[4] = {0.0f, 0.0f, 0.0f, 0.0f};

    // L0 x-gather prefetch for t=0
    int sid = -1;
    uint2 xq0 = {0, 0}, xq1 = {0, 0}, xq2 = {0, 0}, xq3 = {0, 0};
    if (!isL1) {
        sid = a.sidx[b];
        if (sid >= 0) {
            const char* xp = (const char*)a.W0P + (size_t)sid * 4096 + wg * 64 + nh * 8;
            xq0 = *(const uint2*)(xp);
            xq1 = *(const uint2*)(xp + 16);
            xq2 = *(const uint2*)(xp + 32);
            xq3 = *(const uint2*)(xp + 48);
        }
    }

    __syncthreads();   // staging done (only pre-loop barrier)

    for (int tau = 0; tau <= SEQ; ++tau) {
        const bool active = isL1 ? (tau >= 1) : (tau < SEQ);
        if (active) {
            const int t = isL1 ? tau - 1 : tau;
            f32x16 acc;
#pragma unroll
            for (int j = 0; j < 16; ++j) acc[j] = 0.0f;

            if (tau >= 1) {
                // term 1: A = wb1 (LDS), B = h1[tau-1] — stage all 32 h-frags,
                // then MFMA with LDS A-frags in groups of 8.
                const f16* hb1 = a.h1 + (size_t)(tau - 1) * HSTEP;
                uint4 Bh[32];
#pragma unroll
                for (int f = 0; f < 32; ++f)
                    Bh[f] = *(const uint4*)(hb1 + ((f * 2 + nh) * 64 + b) * 8);
#pragma unroll
                for (int g = 0; g < 4; ++g) {
                    f16x8 Af[8];
#pragma unroll
                    for (int j = 0; j < 8; ++j)
                        Af[j] = *(const f16x8*)&wb1[(size_t)((g * 8 + j) * 64 + lane) * 8];
#pragma unroll
                    for (int j = 0; j < 8; ++j)
                        acc = __builtin_amdgcn_mfma_f32_32x32x16_f16(
                            Af[j], __builtin_bit_cast(f16x8, Bh[g * 8 + j]), acc, 0, 0, 0);
                }
                if (isL1 && tau >= 2) {
                    // term 2: A = Whh1 (LDS), B = h2[tau-2] — reuse Bh regs
                    const f16* hb2 = a.h2 + (size_t)(tau - 2) * HSTEP;
#pragma unroll
                    for (int f = 0; f < 32; ++f)
                        Bh[f] = *(const uint4*)(hb2 + ((f * 2 + nh) * 64 + b) * 8);
#pragma unroll
                    for (int g = 0; g < 4; ++g) {
                        f16x8 Af[8];
#pragma unroll
                        for (int j = 0; j < 8; ++j)
                            Af[j] = *(const f16x8*)&wb2[(size_t)((g * 8 + j) * 64 + lane) * 8];
#pragma unroll
                        for (int j = 0; j < 8; ++j)
                            acc = __builtin_amdgcn_mfma_f32_32x32x16_f16(
                                Af[j], __builtin_bit_cast(f16x8, Bh[g * 8 + j]), acc, 0, 0, 0);
                    }
                }
            }

            // ---- cell, fully in-register: lane = batch b, units nh*4+uu ----
            const bool usec = isL1 ? (tau >= 2) : (tau >= 1);
            f16x4 x0 = __builtin_bit_cast(f16x4, xq0);
            f16x4 x1 = __builtin_bit_cast(f16x4, xq1);
            f16x4 x2 = __builtin_bit_cast(f16x4, xq2);
            f16x4 x3 = __builtin_bit_cast(f16x4, xq3);
            f16 hh[4];
#pragma unroll
            for (int uu = 0; uu < 4; ++uu) {
                float gi = acc[uu]      + bf0[uu] + (float)x0[uu];
                float gf = acc[4 + uu]  + bf1[uu] + (float)x1[uu];
                float gg = acc[8 + uu]  + bf2[uu] + (float)x2[uu];
                float go = acc[12 + uu] + bf3[uu] + (float)x3[uu];
                float c_ = usec ? cst[uu] : 0.0f;
                float cn = sigmoidf_(gf) * c_ + sigmoidf_(gi) * tanhf_(gg);
                float hv = sigmoidf_(go) * tanhf_(cn);
                cst[uu] = cn;
                hh[uu] = (f16)hv;
            }
            union { f16x4 h; u64 d; } hp;
            hp.h = (f16x4){hh[0], hh[1], hh[2], hh[3]};
            f16* hbase = isL1 ? a.h2 : a.h1;
            u64* dst = (u64*)(hbase + (size_t)t * HSTEP + ((wg * 64 + b) * 8 + nh * 4));
            __hip_atomic_store(dst, hp.d, __ATOMIC_RELAXED, __HIP_MEMORY_SCOPE_AGENT);
        }

        if (tau < SEQ) {
            // own stores drained -> per-wave global flag (no intra-WG funnel)
            asm volatile("s_waitcnt vmcnt(0)" ::: "memory");
            if (lane == 0)
                __hip_atomic_store(&a.flags[(wg * 4 + w) * 16], (u32)(tau + 1),
                                   __ATOMIC_RELAXED, __HIP_MEMORY_SCOPE_AGENT);

            // x-gather prefetch for tick tau+1 (hidden under the poll)
            if (!isL1 && tau + 1 < SEQ) {
                sid = a.sidx[(tau + 1) * 64 + b];
                if (sid >= 0) {
                    const char* xp = (const char*)a.W0P + (size_t)sid * 4096 + wg * 64 + nh * 8;
                    xq0 = *(const uint2*)(xp);
                    xq1 = *(const uint2*)(xp + 16);
                    xq2 = *(const uint2*)(xp + 32);
                    xq3 = *(const uint2*)(xp + 48);
                } else {
                    xq0 = xq1 = xq2 = xq3 = (uint2){0, 0};
                }
            }

            // poll all 256 wave-flags (4 per lane)
            const u32 want = (u32)(tau + 1);
            int guard = 0;
            while (true) {
                u32 v0 = __hip_atomic_load(&a.flags[lane * 16],
                                           __ATOMIC_RELAXED, __HIP_MEMORY_SCOPE_AGENT);
                u32 v1 = __hip_atomic_load(&a.flags[(lane + 64) * 16],
                                           __ATOMIC_RELAXED, __HIP_MEMORY_SCOPE_AGENT);
                u32 v2 = __hip_atomic_load(&a.flags[(lane + 128) * 16],
                                           __ATOMIC_RELAXED, __HIP_MEMORY_SCOPE_AGENT);
                u32 v3 = __hip_atomic_load(&a.flags[(lane + 192) * 16],
                                           __ATOMIC_RELAXED, __HIP_MEMORY_SCOPE_AGENT);
                u32 mn = min(min(v0, v1), min(v2, v3));
                if (__ballot(mn < want) == 0ull) break;
                __builtin_amdgcn_s_sleep(1);
                if (++guard > (1 << 20)) break;     // visible failure, never hang
            }
            // keep next tick's plain h-loads from hoisting above the poll
            asm volatile("" ::: "memory");
            __builtin_amdgcn_sched_barrier(0);
        }
    }
}

// ---- projection (MFMA): out[b][t][n] = sigmoid(h2[t][b][:] . fcW[n] + fcb[n])
// h2 tiled layout [t][ug][b][8]. block = 4 timesteps x 64 cols; wave = 16 batches.
__global__ __launch_bounds__(256) void proj_mfma(
    const f16* __restrict__ h2, const f16* __restrict__ fcwh,
    const float* __restrict__ fcb, float* __restrict__ out)
{
    const int tg = blockIdx.x >> 4;     // t-group (4 timesteps)
    const int nt = blockIdx.x & 15;     // 64-col group
    const int tid = threadIdx.x;
    const int l = tid & 63;
    const int w = tid >> 6;             // batch-tile
    const int col = l & 15;
    const int kb = l >> 4;

    f32x4 acc[4][4];
#pragma unroll
    for (int j = 0; j < 4; ++j)
#pragma unroll
        for (int v = 0; v < 4; ++v) acc[j][v] = (f32x4){0, 0, 0, 0};

    float fb[4];
#pragma unroll
    for (int v = 0; v < 4; ++v) fb[v] = fcb[nt * 64 + v * 16 + col];

#pragma unroll 2
    for (int f = 0; f < 16; ++f) {
        f16x8 Bf[4];
#pragma unroll
        for (int v = 0; v < 4; ++v) {
            int nn = nt * 64 + v * 16 + col;
            Bf[v] = *(const f16x8*)(fcwh + (size_t)nn * HID + f * 32 + kb * 8);
        }
#pragma unroll
        for (int j = 0; j < 4; ++j) {
            const f16* hp = h2 + (size_t)(tg * 4 + j) * HSTEP
                          + ((f * 4 + kb) * 64 + (w * 16 + col)) * 8;
            uint4 au = *(const uint4*)hp;
#pragma unroll
            for (int v = 0; v < 4; ++v)
                acc[j][v] = __builtin_amdgcn_mfma_f32_16x16x32_f16(
                    __builtin_bit_cast(f16x8, au), Bf[v], acc[j][v], 0, 0, 0);
        }
    }

    // epilogue: C layout col=lane&15, row=(lane>>4)*4+r
#pragma unroll
    for (int j = 0; j < 4; ++j) {
        int t = tg * 4 + j;
#pragma unroll
        for (int v = 0; v < 4; ++v) {
            int nn = nt * 64 + v * 16 + col;
#pragma unroll
            for (int r = 0; r < 4; ++r) {
                int b = w * 16 + kb * 4 + r;
                out[((size_t)b * SEQ + t) * NSK + nn] = sigmoidf_(acc[j][v][r] + fb[v]);
            }
        }
    }
}

extern "C" void kernel_launch(void* const* d_in, const int* in_sizes, int n_in,
                              void* d_out, int out_size, void* d_ws, size_t ws_size,
                              hipStream_t stream) {
    (void)in_sizes; (void)n_in; (void)out_size; (void)ws_size;

    const int*   skills   = (const int*)d_in[0];
    const int*   corrects = (const int*)d_in[1];
    const float* Wih0 = (const float*)d_in[2];
    const float* Whh0 = (const float*)d_in[3];
    const float* bih0 = (const float*)d_in[4];
    const float* bhh0 = (const float*)d_in[5];
    const float* Wih1 = (const float*)d_in[6];
    const float* Whh1 = (const float*)d_in[7];
    const float* bih1 = (const float*)d_in[8];
    const float* bhh1 = (const float*)d_in[9];
    const float* fcW  = (const float*)d_in[10];
    const float* fcb  = (const float*)d_in[11];

    char* ws = (char*)d_ws;
    f16*  h1    = (f16*)(ws + H1_OFF);
    f16*  h2    = (f16*)(ws + H2_OFF);
    f16*  whh0h = (f16*)(ws + WHH0_OFF);
    f16*  wih1h = (f16*)(ws + WIH1_OFF);
    f16*  whh1h = (f16*)(ws + WHH1_OFF);
    f16*  fcwh  = (f16*)(ws + FCW_OFF);
    float* bfold = (float*)(ws + BF_OFF);
    f16*  w0p   = (f16*)(ws + W0P_OFF);
    u32*  flags = (u32*)(ws + FLG_OFF);
    int*  sidx  = (int*)(ws + SIDX_OFF);

    prep_kernel<<<4096, 256, 0, stream>>>(skills, corrects, Whh0, Wih1, Whh1, fcW,
                                          bih0, bhh0, bih1, bhh1,
                                          whh0h, wih1h, whh1h, fcwh,
                                          bfold, sidx, flags);
    w0p_kernel<<<1024, 256, 0, stream>>>(Wih0, w0p);

    PArgs pa;
    pa.sidx = sidx; pa.W0P = w0p;
    pa.Whh0 = whh0h; pa.Wih1 = wih1h; pa.Whh1 = whh1h;
    pa.bfold = bfold; pa.h1 = h1; pa.h2 = h2;
    pa.flags = flags;

    lstm_mfma<<<NWG, 256, 0, stream>>>(pa);

    proj_mfma<<<2048, 256, 0, stream>>>(h2, fcwh, fcb, (float*)d_out);
}

// Round 10
// 3627.245 us; speedup vs baseline: 1.2455x; 1.1029x over previous
//
#include <hip/hip_runtime.h>
#include <hip/hip_fp16.h>

typedef _Float16 f16;
typedef unsigned int u32;
typedef unsigned long long u64;
typedef _Float16 f16x4 __attribute__((ext_vector_type(4)));
typedef _Float16 f16x8 __attribute__((ext_vector_type(8)));
typedef float f32x4 __attribute__((ext_vector_type(4)));
typedef float f32x16 __attribute__((ext_vector_type(16)));

#define SEQ   512
#define HID   512
#define NSK   1024
#define INDIM 2048
#define NWG   64
#define HSTEP 32768   // f16 per timestep, tiled layout [ug=u>>3][b][u&7]
#define WFRAG 16384   // f16 per matrix in wlds: [32 f][64 lane][8]

// ---- workspace layout (bytes) ----
#define H1_OFF    0ull
#define H2_OFF    33554432ull
#define WHH0_OFF  67108864ull
#define WIH1_OFF  69206016ull
#define WHH1_OFF  71303168ull
#define FCW_OFF   73400320ull
#define BF_OFF    74448896ull   // bfold [2][64][32] f32 (16KB)
#define W0P_OFF   74465280ull   // 8 MB: [2048 col][64 wg][32 j] f16, j = gate*8+unit
#define FLG_OFF   82853888ull   // 64 per-WG flag LINES: flags[wg*16 + w] slots
#define SIDX_OFF  82870272ull   // [512 t][64 b] int combined gather index (128KB)

__device__ __forceinline__ float sigmoidf_(float x) {
    return 1.0f / (1.0f + __expf(-x));
}
__device__ __forceinline__ float tanhf_(float x) {
    return 2.0f * sigmoidf_(2.0f * x) - 1.0f;
}

// ---- prep: f16 weights, folded per-WG bias, transposed gather index, flags ----
__global__ __launch_bounds__(256) void prep_kernel(
    const int* __restrict__ skills, const int* __restrict__ corrects,
    const float* __restrict__ Whh0, const float* __restrict__ Wih1,
    const float* __restrict__ Whh1, const float* __restrict__ fcW,
    const float* __restrict__ bih0, const float* __restrict__ bhh0,
    const float* __restrict__ bih1, const float* __restrict__ bhh1,
    f16* __restrict__ whh0h, f16* __restrict__ wih1h,
    f16* __restrict__ whh1h, f16* __restrict__ fcwh,
    float* __restrict__ bfold, int* __restrict__ sidx, u32* __restrict__ flags)
{
    int i = blockIdx.x * 256 + threadIdx.x;
    if (i < 2048 * 512) {
        whh0h[i] = (f16)Whh0[i];
        wih1h[i] = (f16)Wih1[i];
        whh1h[i] = (f16)Whh1[i];
    }
    if (i < 1024 * 512) fcwh[i] = (f16)fcW[i];
    if (i < 4096) {
        int lyr = i >> 11, wgi = (i >> 5) & 63, j = i & 31;
        int row = ((j >> 3) << 9) + wgi * 8 + (j & 7);
        bfold[i] = lyr ? (bih1[row] + bhh1[row]) : (bih0[row] + bhh0[row]);
    }
    if (i < SEQ * 64) {
        int t = i >> 6, b = i & 63;
        int sk = skills[b * SEQ + t], co = corrects[b * SEQ + t];
        sidx[i] = (sk >= 0) ? (sk + NSK * ((co == 1) ? 0 : 1)) : -1;
    }
    if (i < 4096) flags[i] = 0;
}

// ---- W0P build: W0P[c][wg][j] = Wih0[r][c], r = (j>>3)*512 + wg*8 + (j&7) ----
__global__ __launch_bounds__(256) void w0p_kernel(
    const float* __restrict__ Wih0, f16* __restrict__ w0p)
{
    __shared__ float tl[64][65];
    const int tid = threadIdx.x;
    const int ct = blockIdx.x & 31, rt = blockIdx.x >> 5;
    const int r0 = rt * 64, c0 = ct * 64;
#pragma unroll 4
    for (int i = 0; i < 16; ++i) {
        int rr = i * 4 + (tid >> 6);
        int cc = tid & 63;
        tl[rr][cc] = Wih0[(size_t)(r0 + rr) * INDIM + c0 + cc];
    }
    __syncthreads();
    const int jh = r0 >> 9;            // gate (const in tile)
    const int wg0 = (r0 & 511) >> 3;   // first wg chunk
    for (int task = tid; task < 512; task += 256) {
        int c = task >> 3, wgl = task & 7;
        f16 tmp[8];
#pragma unroll
        for (int jl = 0; jl < 8; ++jl) tmp[jl] = (f16)tl[wgl * 8 + jl][c];
        *(f16x8*)&w0p[(size_t)(c0 + c) * 2048 + (wg0 + wgl) * 32 + jh * 8] =
            *(f16x8*)tmp;
    }
}

struct PArgs {
    const int* sidx; const f16* W0P;
    const f16* Whh0; const f16* Wih1; const f16* Whh1;
    const float* bfold;
    f16* h1; f16* h2;
    u32* flags;
};

// ---- persistent MFMA 2-layer LSTM: 64 WGs (1/CU), wave-autonomous ticks ----
// Operand-swapped MFMA: D = W(A) x h^T(B); D col = batch, rows = gate*8+unit.
// Waves: w0 = L0/b0-31, w1 = L1/b0-31, w2 = L1/b32-63, w3 = L0/b32-63.
// ALL weights in fragment-ordered LDS (96KB, 0 bank conflicts — R9 proven).
// SYNC (R10): packed per-WG flag line (4 u32 slots in one 64B line, one per
// wave, sc1-stored after vmcnt drain). ONLY w0 spin-polls the 64 lines
// (lane = wg, same-line 4-slot read, min+ballot); w1-3 wait at ONE
// __syncthreads that w0 joins after detect. 16x less spin traffic than R9's
// 256-wave x 256-line storm — the congestion that inflated every latency leg.
// NO fences anywhere (R2 lesson).
__global__ __launch_bounds__(256, 1) void lstm_mfma(PArgs a) {
    __shared__ f16 wlds[3 * WFRAG];     // 96KB: [m][f][lane][8]

    const int wg   = blockIdx.x;
    const int tid  = threadIdx.x;
    const int lane = tid & 63;
    const int w    = tid >> 6;
    const bool isL1 = (w == 1 || w == 2);
    const int tl   = (w >= 2) ? 1 : 0;       // batch half
    const int n    = lane & 31;
    const int nh   = lane >> 5;
    const int b    = tl * 32 + n;            // batch (B col / cell lane)

    // stage Whh0 / Wih1 / Whh1 -> LDS, per-lane fragment order:
    // wlds[m][f][l] = M[row(l&31)][f*16 + (l>>5)*8 .. +8], row(ln) per A-row map
    for (int i = tid; i < 3 * 2048; i += 256) {
        int m = i >> 11, rem = i & 2047;
        int f = rem >> 6, l = rem & 63;
        int ln = l & 31, lh = l >> 5;
        int rr = ((ln >> 3) << 9) + wg * 8 + (ln & 7);
        const f16* src = (m == 0) ? a.Whh0 : ((m == 1) ? a.Wih1 : a.Whh1);
        *(uint4*)&wlds[(size_t)i * 8] =
            *(const uint4*)(src + (size_t)rr * HID + f * 16 + lh * 8);
    }

    const f16* wb1 = wlds + (size_t)(isL1 ? 1 : 0) * WFRAG;   // term-1 matrix
    const f16* wb2 = wlds + (size_t)2 * WFRAG;                // Whh1 (term 2)

    // bias: bf{g}[uu] for unit nh*4+uu, gate g
    float4 bf0, bf1, bf2, bf3;
    {
        const float* bp = a.bfold + (isL1 ? 2048 : 0) + wg * 32 + nh * 4;
        bf0 = *(const float4*)(bp + 0);
        bf1 = *(const float4*)(bp + 8);
        bf2 = *(const float4*)(bp + 16);
        bf3 = *(const float4*)(bp + 24);
    }

    float cst[4] = {0.0f, 0.0f, 0.0f, 0.0f};

    // L0 x-gather prefetch for t=0
    int sid = -1;
    uint2 xq0 = {0, 0}, xq1 = {0, 0}, xq2 = {0, 0}, xq3 = {0, 0};
    if (!isL1) {
        sid = a.sidx[b];
        if (sid >= 0) {
            const char* xp = (const char*)a.W0P + (size_t)sid * 4096 + wg * 64 + nh * 8;
            xq0 = *(const uint2*)(xp);
            xq1 = *(const uint2*)(xp + 16);
            xq2 = *(const uint2*)(xp + 32);
            xq3 = *(const uint2*)(xp + 48);
        }
    }

    __syncthreads();   // staging done

    for (int tau = 0; tau <= SEQ; ++tau) {
        const bool active = isL1 ? (tau >= 1) : (tau < SEQ);
        if (active) {
            const int t = isL1 ? tau - 1 : tau;
            f32x16 acc;
#pragma unroll
            for (int j = 0; j < 16; ++j) acc[j] = 0.0f;

            if (tau >= 1) {
                // term 1: A = wb1 (LDS), B = h1[tau-1] — stage all 32 h-frags,
                // then MFMA with LDS A-frags in groups of 8.
                const f16* hb1 = a.h1 + (size_t)(tau - 1) * HSTEP;
                uint4 Bh[32];
#pragma unroll
                for (int f = 0; f < 32; ++f)
                    Bh[f] = *(const uint4*)(hb1 + ((f * 2 + nh) * 64 + b) * 8);
#pragma unroll
                for (int g = 0; g < 4; ++g) {
                    f16x8 Af[8];
#pragma unroll
                    for (int j = 0; j < 8; ++j)
                        Af[j] = *(const f16x8*)&wb1[(size_t)((g * 8 + j) * 64 + lane) * 8];
#pragma unroll
                    for (int j = 0; j < 8; ++j)
                        acc = __builtin_amdgcn_mfma_f32_32x32x16_f16(
                            Af[j], __builtin_bit_cast(f16x8, Bh[g * 8 + j]), acc, 0, 0, 0);
                }
                if (isL1 && tau >= 2) {
                    // term 2: A = Whh1 (LDS), B = h2[tau-2] — reuse Bh regs
                    const f16* hb2 = a.h2 + (size_t)(tau - 2) * HSTEP;
#pragma unroll
                    for (int f = 0; f < 32; ++f)
                        Bh[f] = *(const uint4*)(hb2 + ((f * 2 + nh) * 64 + b) * 8);
#pragma unroll
                    for (int g = 0; g < 4; ++g) {
                        f16x8 Af[8];
#pragma unroll
                        for (int j = 0; j < 8; ++j)
                            Af[j] = *(const f16x8*)&wb2[(size_t)((g * 8 + j) * 64 + lane) * 8];
#pragma unroll
                        for (int j = 0; j < 8; ++j)
                            acc = __builtin_amdgcn_mfma_f32_32x32x16_f16(
                                Af[j], __builtin_bit_cast(f16x8, Bh[g * 8 + j]), acc, 0, 0, 0);
                    }
                }
            }

            // ---- cell, fully in-register: lane = batch b, units nh*4+uu ----
            const bool usec = isL1 ? (tau >= 2) : (tau >= 1);
            f16x4 x0 = __builtin_bit_cast(f16x4, xq0);
            f16x4 x1 = __builtin_bit_cast(f16x4, xq1);
            f16x4 x2 = __builtin_bit_cast(f16x4, xq2);
            f16x4 x3 = __builtin_bit_cast(f16x4, xq3);
            f16 hh[4];
#pragma unroll
            for (int uu = 0; uu < 4; ++uu) {
                float gi = acc[uu]      + bf0[uu] + (float)x0[uu];
                float gf = acc[4 + uu]  + bf1[uu] + (float)x1[uu];
                float gg = acc[8 + uu]  + bf2[uu] + (float)x2[uu];
                float go = acc[12 + uu] + bf3[uu] + (float)x3[uu];
                float c_ = usec ? cst[uu] : 0.0f;
                float cn = sigmoidf_(gf) * c_ + sigmoidf_(gi) * tanhf_(gg);
                float hv = sigmoidf_(go) * tanhf_(cn);
                cst[uu] = cn;
                hh[uu] = (f16)hv;
            }
            union { f16x4 h; u64 d; } hp;
            hp.h = (f16x4){hh[0], hh[1], hh[2], hh[3]};
            f16* hbase = isL1 ? a.h2 : a.h1;
            u64* dst = (u64*)(hbase + (size_t)t * HSTEP + ((wg * 64 + b) * 8 + nh * 4));
            __hip_atomic_store(dst, hp.d, __ATOMIC_RELAXED, __HIP_MEMORY_SCOPE_AGENT);
        }

        if (tau < SEQ) {
            // own stores drained -> this wave's slot in the WG's packed flag line
            asm volatile("s_waitcnt vmcnt(0)" ::: "memory");
            if (lane == 0)
                __hip_atomic_store(&a.flags[wg * 16 + w], (u32)(tau + 1),
                                   __ATOMIC_RELAXED, __HIP_MEMORY_SCOPE_AGENT);

            // x-gather prefetch for tick tau+1 (completes during spin/barrier)
            if (!isL1 && tau + 1 < SEQ) {
                sid = a.sidx[(tau + 1) * 64 + b];
                if (sid >= 0) {
                    const char* xp = (const char*)a.W0P + (size_t)sid * 4096 + wg * 64 + nh * 8;
                    xq0 = *(const uint2*)(xp);
                    xq1 = *(const uint2*)(xp + 16);
                    xq2 = *(const uint2*)(xp + 32);
                    xq3 = *(const uint2*)(xp + 48);
                } else {
                    xq0 = xq1 = xq2 = xq3 = (uint2){0, 0};
                }
            }

            // ONE spinner per WG: w0 polls all 64 packed lines (lane = wg);
            // siblings wait at the barrier below.
            if (w == 0) {
                const u32 want = (u32)(tau + 1);
                const u32* fp = a.flags + lane * 16;
                int guard = 0;
                while (true) {
                    u32 v0 = __hip_atomic_load(fp + 0, __ATOMIC_RELAXED,
                                               __HIP_MEMORY_SCOPE_AGENT);
                    u32 v1 = __hip_atomic_load(fp + 1, __ATOMIC_RELAXED,
                                               __HIP_MEMORY_SCOPE_AGENT);
                    u32 v2 = __hip_atomic_load(fp + 2, __ATOMIC_RELAXED,
                                               __HIP_MEMORY_SCOPE_AGENT);
                    u32 v3 = __hip_atomic_load(fp + 3, __ATOMIC_RELAXED,
                                               __HIP_MEMORY_SCOPE_AGENT);
                    u32 mn = min(min(v0, v1), min(v2, v3));
                    if (__ballot(mn < want) == 0ull) break;
                    __builtin_amdgcn_s_sleep(1);
                    if (++guard > (1 << 20)) break;   // visible failure, never hang
                }
            }
            __syncthreads();   // w0 joins after detect -> releases w1-w3
            // keep next tick's plain h-loads from hoisting above the release
            asm volatile("" ::: "memory");
            __builtin_amdgcn_sched_barrier(0);
        }
    }
}

// ---- projection (MFMA): out[b][t][n] = sigmoid(h2[t][b][:] . fcW[n] + fcb[n])
// h2 tiled layout [t][ug][b][8]. block = 4 timesteps x 64 cols; wave = 16 batches.
__global__ __launch_bounds__(256) void proj_mfma(
    const f16* __restrict__ h2, const f16* __restrict__ fcwh,
    const float* __restrict__ fcb, float* __restrict__ out)
{
    const int tg = blockIdx.x >> 4;     // t-group (4 timesteps)
    const int nt = blockIdx.x & 15;     // 64-col group
    const int tid = threadIdx.x;
    const int l = tid & 63;
    const int w = tid >> 6;             // batch-tile
    const int col = l & 15;
    const int kb = l >> 4;

    f32x4 acc[4][4];
#pragma unroll
    for (int j = 0; j < 4; ++j)
#pragma unroll
        for (int v = 0; v < 4; ++v) acc[j][v] = (f32x4){0, 0, 0, 0};

    float fb[4];
#pragma unroll
    for (int v = 0; v < 4; ++v) fb[v] = fcb[nt * 64 + v * 16 + col];

#pragma unroll 2
    for (int f = 0; f < 16; ++f) {
        f16x8 Bf[4];
#pragma unroll
        for (int v = 0; v < 4; ++v) {
            int nn = nt * 64 + v * 16 + col;
            Bf[v] = *(const f16x8*)(fcwh + (size_t)nn * HID + f * 32 + kb * 8);
        }
#pragma unroll
        for (int j = 0; j < 4; ++j) {
            const f16* hp = h2 + (size_t)(tg * 4 + j) * HSTEP
                          + ((f * 4 + kb) * 64 + (w * 16 + col)) * 8;
            uint4 au = *(const uint4*)hp;
#pragma unroll
            for (int v = 0; v < 4; ++v)
                acc[j][v] = __builtin_amdgcn_mfma_f32_16x16x32_f16(
                    __builtin_bit_cast(f16x8, au), Bf[v], acc[j][v], 0, 0, 0);
        }
    }

    // epilogue: C layout col=lane&15, row=(lane>>4)*4+r
#pragma unroll
    for (int j = 0; j < 4; ++j) {
        int t = tg * 4 + j;
#pragma unroll
        for (int v = 0; v < 4; ++v) {
            int nn = nt * 64 + v * 16 + col;
#pragma unroll
            for (int r = 0; r < 4; ++r) {
                int b = w * 16 + kb * 4 + r;
                out[((size_t)b * SEQ + t) * NSK + nn] = sigmoidf_(acc[j][v][r] + fb[v]);
            }
        }
    }
}

extern "C" void kernel_launch(void* const* d_in, const int* in_sizes, int n_in,
                              void* d_out, int out_size, void* d_ws, size_t ws_size,
                              hipStream_t stream) {
    (void)in_sizes; (void)n_in; (void)out_size; (void)ws_size;

    const int*   skills   = (const int*)d_in[0];
    const int*   corrects = (const int*)d_in[1];
    const float* Wih0 = (const float*)d_in[2];
    const float* Whh0 = (const float*)d_in[3];
    const float* bih0 = (const float*)d_in[4];
    const float* bhh0 = (const float*)d_in[5];
    const float* Wih1 = (const float*)d_in[6];
    const float* Whh1 = (const float*)d_in[7];
    const float* bih1 = (const float*)d_in[8];
    const float* bhh1 = (const float*)d_in[9];
    const float* fcW  = (const float*)d_in[10];
    const float* fcb  = (const float*)d_in[11];

    char* ws = (char*)d_ws;
    f16*  h1    = (f16*)(ws + H1_OFF);
    f16*  h2    = (f16*)(ws + H2_OFF);
    f16*  whh0h = (f16*)(ws + WHH0_OFF);
    f16*  wih1h = (f16*)(ws + WIH1_OFF);
    f16*  whh1h = (f16*)(ws + WHH1_OFF);
    f16*  fcwh  = (f16*)(ws + FCW_OFF);
    float* bfold = (float*)(ws + BF_OFF);
    f16*  w0p   = (f16*)(ws + W0P_OFF);
    u32*  flags = (u32*)(ws + FLG_OFF);
    int*  sidx  = (int*)(ws + SIDX_OFF);

    prep_kernel<<<4096, 256, 0, stream>>>(skills, corrects, Whh0, Wih1, Whh1, fcW,
                                          bih0, bhh0, bih1, bhh1,
                                          whh0h, wih1h, whh1h, fcwh,
                                          bfold, sidx, flags);
    w0p_kernel<<<1024, 256, 0, stream>>>(Wih0, w0p);

    PArgs pa;
    pa.sidx = sidx; pa.W0P = w0p;
    pa.Whh0 = whh0h; pa.Wih1 = wih1h; pa.Whh1 = whh1h;
    pa.bfold = bfold; pa.h1 = h1; pa.h2 = h2;
    pa.flags = flags;

    lstm_mfma<<<NWG, 256, 0, stream>>>(pa);

    proj_mfma<<<2048, 256, 0, stream>>>(h2, fcwh, fcb, (float*)d_out);
}

// Round 11
// 3139.894 us; speedup vs baseline: 1.4388x; 1.1552x over previous
//
#include <hip/hip_runtime.h>
#include <hip/hip_fp16.h>

typedef _Float16 f16;
typedef unsigned int u32;
typedef unsigned long long u64;
typedef _Float16 f16x4 __attribute__((ext_vector_type(4)));
typedef _Float16 f16x8 __attribute__((ext_vector_type(8)));
typedef float f32x4 __attribute__((ext_vector_type(4)));
typedef float f32x16 __attribute__((ext_vector_type(16)));

#define SEQ   512
#define HID   512
#define NSK   1024
#define INDIM 2048
#define NWG   64
#define HSTEP 32768   // f16 per timestep, tiled layout [ug=u>>3][b][u&7]
#define WFRAG 16384   // f16 per matrix in wlds: [32 f][64 lane][8]

// ---- workspace layout (bytes) ----
#define H1_OFF    0ull
#define H2_OFF    33554432ull
#define WHH0_OFF  67108864ull
#define WIH1_OFF  69206016ull
#define WHH1_OFF  71303168ull
#define FCW_OFF   73400320ull
#define BF_OFF    74448896ull   // bfold [2][64][32] f32 (16KB)
#define W0P_OFF   74465280ull   // 8 MB: [2048 col][64 wg][32 j] f16, j = gate*8+unit
#define FLG_OFF   82853888ull   // 64 per-WG flag LINES: flags[wg*16 + w] slots
#define SIDX_OFF  82870272ull   // [512 t][64 b] int combined gather index (128KB)

__device__ __forceinline__ float sigmoidf_(float x) {
    return 1.0f / (1.0f + __expf(-x));
}
__device__ __forceinline__ float tanhf_(float x) {
    return 2.0f * sigmoidf_(2.0f * x) - 1.0f;
}

// Far-atomic stores: agent-scope atomic EXCHANGE executes at the MALL (the
// cross-XCD coherence point) and leaves the line dirty THERE — h/flag data
// stays MALL-resident instead of writing through to HBM (R10 lesson:
// sc1 write-through stores cost an HBM round trip on every consumer XCD).
__device__ __forceinline__ void mall_store64(u64* p, u64 v) {
    (void)__hip_atomic_exchange(p, v, __ATOMIC_RELAXED, __HIP_MEMORY_SCOPE_AGENT);
}
__device__ __forceinline__ void mall_store32(u32* p, u32 v) {
    (void)__hip_atomic_exchange(p, v, __ATOMIC_RELAXED, __HIP_MEMORY_SCOPE_AGENT);
}

// ---- prep: f16 weights, folded per-WG bias, transposed gather index, flags ----
__global__ __launch_bounds__(256) void prep_kernel(
    const int* __restrict__ skills, const int* __restrict__ corrects,
    const float* __restrict__ Whh0, const float* __restrict__ Wih1,
    const float* __restrict__ Whh1, const float* __restrict__ fcW,
    const float* __restrict__ bih0, const float* __restrict__ bhh0,
    const float* __restrict__ bih1, const float* __restrict__ bhh1,
    f16* __restrict__ whh0h, f16* __restrict__ wih1h,
    f16* __restrict__ whh1h, f16* __restrict__ fcwh,
    float* __restrict__ bfold, int* __restrict__ sidx, u32* __restrict__ flags)
{
    int i = blockIdx.x * 256 + threadIdx.x;
    if (i < 2048 * 512) {
        whh0h[i] = (f16)Whh0[i];
        wih1h[i] = (f16)Wih1[i];
        whh1h[i] = (f16)Whh1[i];
    }
    if (i < 1024 * 512) fcwh[i] = (f16)fcW[i];
    if (i < 4096) {
        int lyr = i >> 11, wgi = (i >> 5) & 63, j = i & 31;
        int row = ((j >> 3) << 9) + wgi * 8 + (j & 7);
        bfold[i] = lyr ? (bih1[row] + bhh1[row]) : (bih0[row] + bhh0[row]);
    }
    if (i < SEQ * 64) {
        int t = i >> 6, b = i & 63;
        int sk = skills[b * SEQ + t], co = corrects[b * SEQ + t];
        sidx[i] = (sk >= 0) ? (sk + NSK * ((co == 1) ? 0 : 1)) : -1;
    }
    if (i < 4096) mall_store32(&flags[i], 0u);   // flags live at MALL from the start
}

// ---- W0P build: W0P[c][wg][j] = Wih0[r][c], r = (j>>3)*512 + wg*8 + (j&7) ----
__global__ __launch_bounds__(256) void w0p_kernel(
    const float* __restrict__ Wih0, f16* __restrict__ w0p)
{
    __shared__ float tl[64][65];
    const int tid = threadIdx.x;
    const int ct = blockIdx.x & 31, rt = blockIdx.x >> 5;
    const int r0 = rt * 64, c0 = ct * 64;
#pragma unroll 4
    for (int i = 0; i < 16; ++i) {
        int rr = i * 4 + (tid >> 6);
        int cc = tid & 63;
        tl[rr][cc] = Wih0[(size_t)(r0 + rr) * INDIM + c0 + cc];
    }
    __syncthreads();
    const int jh = r0 >> 9;            // gate (const in tile)
    const int wg0 = (r0 & 511) >> 3;   // first wg chunk
    for (int task = tid; task < 512; task += 256) {
        int c = task >> 3, wgl = task & 7;
        f16 tmp[8];
#pragma unroll
        for (int jl = 0; jl < 8; ++jl) tmp[jl] = (f16)tl[wgl * 8 + jl][c];
        *(f16x8*)&w0p[(size_t)(c0 + c) * 2048 + (wg0 + wgl) * 32 + jh * 8] =
            *(f16x8*)tmp;
    }
}

struct PArgs {
    const int* sidx; const f16* W0P;
    const f16* Whh0; const f16* Wih1; const f16* Whh1;
    const float* bfold;
    f16* h1; f16* h2;
    u32* flags;
};

// ---- persistent MFMA 2-layer LSTM: 64 WGs (1/CU), wave-autonomous ticks ----
// Operand-swapped MFMA: D = W(A) x h^T(B); D col = batch, rows = gate*8+unit.
// Waves: w0 = L0/b0-31, w1 = L1/b0-31, w2 = L1/b32-63, w3 = L0/b32-63.
// ALL weights in fragment-ordered LDS (96KB, 0 bank conflicts — R9 proven).
// h + flags via far-atomic exchange (MALL-resident, R11); h loads plain
// (L2-allocating, first-touch-per-XCD fresh). Packed per-WG flag line; one
// spinner wave per WG + syncthreads release (R10). NO fences (R2).
__global__ __launch_bounds__(256, 1) void lstm_mfma(PArgs a) {
    __shared__ f16 wlds[3 * WFRAG];     // 96KB: [m][f][lane][8]

    const int wg   = blockIdx.x;
    const int tid  = threadIdx.x;
    const int lane = tid & 63;
    const int w    = tid >> 6;
    const bool isL1 = (w == 1 || w == 2);
    const int tl   = (w >= 2) ? 1 : 0;       // batch half
    const int n    = lane & 31;
    const int nh   = lane >> 5;
    const int b    = tl * 32 + n;            // batch (B col / cell lane)

    // stage Whh0 / Wih1 / Whh1 -> LDS, per-lane fragment order
    for (int i = tid; i < 3 * 2048; i += 256) {
        int m = i >> 11, rem = i & 2047;
        int f = rem >> 6, l = rem & 63;
        int ln = l & 31, lh = l >> 5;
        int rr = ((ln >> 3) << 9) + wg * 8 + (ln & 7);
        const f16* src = (m == 0) ? a.Whh0 : ((m == 1) ? a.Wih1 : a.Whh1);
        *(uint4*)&wlds[(size_t)i * 8] =
            *(const uint4*)(src + (size_t)rr * HID + f * 16 + lh * 8);
    }

    const f16* wb1 = wlds + (size_t)(isL1 ? 1 : 0) * WFRAG;   // term-1 matrix
    const f16* wb2 = wlds + (size_t)2 * WFRAG;                // Whh1 (term 2)

    // bias: bf{g}[uu] for unit nh*4+uu, gate g
    float4 bf0, bf1, bf2, bf3;
    {
        const float* bp = a.bfold + (isL1 ? 2048 : 0) + wg * 32 + nh * 4;
        bf0 = *(const float4*)(bp + 0);
        bf1 = *(const float4*)(bp + 8);
        bf2 = *(const float4*)(bp + 16);
        bf3 = *(const float4*)(bp + 24);
    }

    float cst[4] = {0.0f, 0.0f, 0.0f, 0.0f};

    // L0 x-gather prefetch for t=0
    int sid = -1;
    uint2 xq0 = {0, 0}, xq1 = {0, 0}, xq2 = {0, 0}, xq3 = {0, 0};
    if (!isL1) {
        sid = a.sidx[b];
        if (sid >= 0) {
            const char* xp = (const char*)a.W0P + (size_t)sid * 4096 + wg * 64 + nh * 8;
            xq0 = *(const uint2*)(xp);
            xq1 = *(const uint2*)(xp + 16);
            xq2 = *(const uint2*)(xp + 32);
            xq3 = *(const uint2*)(xp + 48);
        }
    }

    __syncthreads();   // staging done

    for (int tau = 0; tau <= SEQ; ++tau) {
        const bool active = isL1 ? (tau >= 1) : (tau < SEQ);
        if (active) {
            const int t = isL1 ? tau - 1 : tau;
            f32x16 acc;
#pragma unroll
            for (int j = 0; j < 16; ++j) acc[j] = 0.0f;

            if (tau >= 1) {
                const bool t2 = isL1 && (tau >= 2);
                // stage ALL h fragments up front: one MALL round trip covers
                // both terms (h is MALL-dirty via far-atomic stores).
                const f16* hb1 = a.h1 + (size_t)(tau - 1) * HSTEP;
                const f16* hb2 = a.h2 + (size_t)(tau - 2) * HSTEP;
                uint4 Bh1[32], Bh2[32];
#pragma unroll
                for (int f = 0; f < 32; ++f)
                    Bh1[f] = *(const uint4*)(hb1 + ((f * 2 + nh) * 64 + b) * 8);
                if (t2) {
#pragma unroll
                    for (int f = 0; f < 32; ++f)
                        Bh2[f] = *(const uint4*)(hb2 + ((f * 2 + nh) * 64 + b) * 8);
                }
                // term 1: A = wb1 (LDS), B = h1[tau-1]
#pragma unroll
                for (int g = 0; g < 4; ++g) {
                    f16x8 Af[8];
#pragma unroll
                    for (int j = 0; j < 8; ++j)
                        Af[j] = *(const f16x8*)&wb1[(size_t)((g * 8 + j) * 64 + lane) * 8];
#pragma unroll
                    for (int j = 0; j < 8; ++j)
                        acc = __builtin_amdgcn_mfma_f32_32x32x16_f16(
                            Af[j], __builtin_bit_cast(f16x8, Bh1[g * 8 + j]), acc, 0, 0, 0);
                }
                // term 2: A = Whh1 (LDS), B = h2[tau-2]
                if (t2) {
#pragma unroll
                    for (int g = 0; g < 4; ++g) {
                        f16x8 Af[8];
#pragma unroll
                        for (int j = 0; j < 8; ++j)
                            Af[j] = *(const f16x8*)&wb2[(size_t)((g * 8 + j) * 64 + lane) * 8];
#pragma unroll
                        for (int j = 0; j < 8; ++j)
                            acc = __builtin_amdgcn_mfma_f32_32x32x16_f16(
                                Af[j], __builtin_bit_cast(f16x8, Bh2[g * 8 + j]), acc, 0, 0, 0);
                    }
                }
            }

            // ---- cell, fully in-register: lane = batch b, units nh*4+uu ----
            const bool usec = isL1 ? (tau >= 2) : (tau >= 1);
            f16x4 x0 = __builtin_bit_cast(f16x4, xq0);
            f16x4 x1 = __builtin_bit_cast(f16x4, xq1);
            f16x4 x2 = __builtin_bit_cast(f16x4, xq2);
            f16x4 x3 = __builtin_bit_cast(f16x4, xq3);
            f16 hh[4];
#pragma unroll
            for (int uu = 0; uu < 4; ++uu) {
                float gi = acc[uu]      + bf0[uu] + (float)x0[uu];
                float gf = acc[4 + uu]  + bf1[uu] + (float)x1[uu];
                float gg = acc[8 + uu]  + bf2[uu] + (float)x2[uu];
                float go = acc[12 + uu] + bf3[uu] + (float)x3[uu];
                float c_ = usec ? cst[uu] : 0.0f;
                float cn = sigmoidf_(gf) * c_ + sigmoidf_(gi) * tanhf_(gg);
                float hv = sigmoidf_(go) * tanhf_(cn);
                cst[uu] = cn;
                hh[uu] = (f16)hv;
            }
            union { f16x4 h; u64 d; } hp;
            hp.h = (f16x4){hh[0], hh[1], hh[2], hh[3]};
            f16* hbase = isL1 ? a.h2 : a.h1;
            u64* dst = (u64*)(hbase + (size_t)t * HSTEP + ((wg * 64 + b) * 8 + nh * 4));
            mall_store64(dst, hp.d);   // far atomic -> line stays dirty in MALL
        }

        if (tau < SEQ) {
            // own atomics retired -> this wave's slot in the WG's packed flag line
            asm volatile("s_waitcnt vmcnt(0)" ::: "memory");
            if (lane == 0)
                mall_store32(&a.flags[wg * 16 + w], (u32)(tau + 1));

            // x-gather prefetch for tick tau+1 (completes during spin/barrier)
            if (!isL1 && tau + 1 < SEQ) {
                sid = a.sidx[(tau + 1) * 64 + b];
                if (sid >= 0) {
                    const char* xp = (const char*)a.W0P + (size_t)sid * 4096 + wg * 64 + nh * 8;
                    xq0 = *(const uint2*)(xp);
                    xq1 = *(const uint2*)(xp + 16);
                    xq2 = *(const uint2*)(xp + 32);
                    xq3 = *(const uint2*)(xp + 48);
                } else {
                    xq0 = xq1 = xq2 = xq3 = (uint2){0, 0};
                }
            }

            // ONE spinner per WG: w0 polls all 64 packed lines (lane = wg);
            // sc1 atomic loads read the MALL-dirty lines directly.
            if (w == 0) {
                const u32 want = (u32)(tau + 1);
                const u32* fp = a.flags + lane * 16;
                int guard = 0;
                while (true) {
                    u32 v0 = __hip_atomic_load(fp + 0, __ATOMIC_RELAXED,
                                               __HIP_MEMORY_SCOPE_AGENT);
                    u32 v1 = __hip_atomic_load(fp + 1, __ATOMIC_RELAXED,
                                               __HIP_MEMORY_SCOPE_AGENT);
                    u32 v2 = __hip_atomic_load(fp + 2, __ATOMIC_RELAXED,
                                               __HIP_MEMORY_SCOPE_AGENT);
                    u32 v3 = __hip_atomic_load(fp + 3, __ATOMIC_RELAXED,
                                               __HIP_MEMORY_SCOPE_AGENT);
                    u32 mn = min(min(v0, v1), min(v2, v3));
                    if (__ballot(mn < want) == 0ull) break;
                    __builtin_amdgcn_s_sleep(1);
                    if (++guard > (1 << 20)) break;   // visible failure, never hang
                }
            }
            __syncthreads();   // w0 joins after detect -> releases w1-w3
            // keep next tick's plain h-loads from hoisting above the release
            asm volatile("" ::: "memory");
            __builtin_amdgcn_sched_barrier(0);
        }
    }
}

// ---- projection (MFMA): out[b][t][n] = sigmoid(h2[t][b][:] . fcW[n] + fcb[n])
// h2 tiled layout [t][ug][b][8]. block = 4 timesteps x 64 cols; wave = 16 batches.
__global__ __launch_bounds__(256) void proj_mfma(
    const f16* __restrict__ h2, const f16* __restrict__ fcwh,
    const float* __restrict__ fcb, float* __restrict__ out)
{
    const int tg = blockIdx.x >> 4;     // t-group (4 timesteps)
    const int nt = blockIdx.x & 15;     // 64-col group
    const int tid = threadIdx.x;
    const int l = tid & 63;
    const int w = tid >> 6;             // batch-tile
    const int col = l & 15;
    const int kb = l >> 4;

    f32x4 acc[4][4];
#pragma unroll
    for (int j = 0; j < 4; ++j)
#pragma unroll
        for (int v = 0; v < 4; ++v) acc[j][v] = (f32x4){0, 0, 0, 0};

    float fb[4];
#pragma unroll
    for (int v = 0; v < 4; ++v) fb[v] = fcb[nt * 64 + v * 16 + col];

#pragma unroll 2
    for (int f = 0; f < 16; ++f) {
        f16x8 Bf[4];
#pragma unroll
        for (int v = 0; v < 4; ++v) {
            int nn = nt * 64 + v * 16 + col;
            Bf[v] = *(const f16x8*)(fcwh + (size_t)nn * HID + f * 32 + kb * 8);
        }
#pragma unroll
        for (int j = 0; j < 4; ++j) {
            const f16* hp = h2 + (size_t)(tg * 4 + j) * HSTEP
                          + ((f * 4 + kb) * 64 + (w * 16 + col)) * 8;
            uint4 au = *(const uint4*)hp;
#pragma unroll
            for (int v = 0; v < 4; ++v)
                acc[j][v] = __builtin_amdgcn_mfma_f32_16x16x32_f16(
                    __builtin_bit_cast(f16x8, au), Bf[v], acc[j][v], 0, 0, 0);
        }
    }

    // epilogue: C layout col=lane&15, row=(lane>>4)*4+r
#pragma unroll
    for (int j = 0; j < 4; ++j) {
        int t = tg * 4 + j;
#pragma unroll
        for (int v = 0; v < 4; ++v) {
            int nn = nt * 64 + v * 16 + col;
#pragma unroll
            for (int r = 0; r < 4; ++r) {
                int b = w * 16 + kb * 4 + r;
                out[((size_t)b * SEQ + t) * NSK + nn] = sigmoidf_(acc[j][v][r] + fb[v]);
            }
        }
    }
}

extern "C" void kernel_launch(void* const* d_in, const int* in_sizes, int n_in,
                              void* d_out, int out_size, void* d_ws, size_t ws_size,
                              hipStream_t stream) {
    (void)in_sizes; (void)n_in; (void)out_size; (void)ws_size;

    const int*   skills   = (const int*)d_in[0];
    const int*   corrects = (const int*)d_in[1];
    const float* Wih0 = (const float*)d_in[2];
    const float* Whh0 = (const float*)d_in[3];
    const float* bih0 = (const float*)d_in[4];
    const float* bhh0 = (const float*)d_in[5];
    const float* Wih1 = (const float*)d_in[6];
    const float* Whh1 = (const float*)d_in[7];
    const float* bih1 = (const float*)d_in[8];
    const float* bhh1 = (const float*)d_in[9];
    const float* fcW  = (const float*)d_in[10];
    const float* fcb  = (const float*)d_in[11];

    char* ws = (char*)d_ws;
    f16*  h1    = (f16*)(ws + H1_OFF);
    f16*  h2    = (f16*)(ws + H2_OFF);
    f16*  whh0h = (f16*)(ws + WHH0_OFF);
    f16*  wih1h = (f16*)(ws + WIH1_OFF);
    f16*  whh1h = (f16*)(ws + WHH1_OFF);
    f16*  fcwh  = (f16*)(ws + FCW_OFF);
    float* bfold = (float*)(ws + BF_OFF);
    f16*  w0p   = (f16*)(ws + W0P_OFF);
    u32*  flags = (u32*)(ws + FLG_OFF);
    int*  sidx  = (int*)(ws + SIDX_OFF);

    prep_kernel<<<4096, 256, 0, stream>>>(skills, corrects, Whh0, Wih1, Whh1, fcW,
                                          bih0, bhh0, bih1, bhh1,
                                          whh0h, wih1h, whh1h, fcwh,
                                          bfold, sidx, flags);
    w0p_kernel<<<1024, 256, 0, stream>>>(Wih0, w0p);

    PArgs pa;
    pa.sidx = sidx; pa.W0P = w0p;
    pa.Whh0 = whh0h; pa.Wih1 = wih1h; pa.Whh1 = whh1h;
    pa.bfold = bfold; pa.h1 = h1; pa.h2 = h2;
    pa.flags = flags;

    lstm_mfma<<<NWG, 256, 0, stream>>>(pa);

    proj_mfma<<<2048, 256, 0, stream>>>(h2, fcwh, fcb, (float*)d_out);
}